// Round 1
// 492.956 us; speedup vs baseline: 1.0314x; 1.0314x over previous
//
#include <hip/hip_runtime.h>
#include <cmath>

#define DIM 1024
#define DIM_INNER 2048
#define BATCH 4
#define SEQ 4096
#define MTOT (BATCH * SEQ)
#define CHUNK 32
#define NCHUNK (SEQ / CHUNK)        // 128 chunks per sequence

typedef __bf16 bf16x8 __attribute__((ext_vector_type(8)));
typedef short short8_t __attribute__((ext_vector_type(8)));
typedef float floatx4 __attribute__((ext_vector_type(4)));
typedef unsigned short u16x4 __attribute__((ext_vector_type(4)));
typedef unsigned int uint4_t __attribute__((ext_vector_type(4)));
typedef float float4_t __attribute__((ext_vector_type(4)));
typedef unsigned short ushort_t;

__device__ __forceinline__ unsigned short f2bf(float f) {
  unsigned int u = __builtin_bit_cast(unsigned int, f);
  u += 0x7fffu + ((u >> 16) & 1u);   // round-to-nearest-even
  return (unsigned short)(u >> 16);
}
__device__ __forceinline__ float bflo2f(unsigned int u) {
  return __builtin_bit_cast(float, u << 16);
}
__device__ __forceinline__ float bfhi2f(unsigned int u) {
  return __builtin_bit_cast(float, u & 0xffff0000u);
}

// Fast (native v_exp/v_log) log-space terms from (h, g):
//   lc = -softplus(g) ;  lv = -softplus(-g) + log_g(h) = g + lc + log_g(h)
__device__ __forceinline__ void lclv_fast(float h, float g, float& lc, float& lv) {
  float eg = __expf(-fabsf(g));
  float sp = fmaxf(g, 0.f) + __logf(1.f + eg);
  lc = -sp;
  float eh = __expf(h);
  float t  = (h >= 0.f) ? (h + 0.5f) : (1.f + eh);
  float lt = __logf(t);
  float lg = (h >= 0.f) ? lt : (h - lt);
  lv = g + lc + lg;
}
// a may be -inf; b finite
__device__ __forceinline__ float logaddexp_f(float a, float b) {
  float m = fmaxf(a, b);
  return m + __logf(1.f + __expf(-fabsf(a - b)));
}

// async 16B/lane global->LDS; dest = wave-uniform base + lane*16
__device__ __forceinline__ void async_copy16(const ushort_t* g, ushort_t* l) {
  __builtin_amdgcn_global_load_lds(
      (const __attribute__((address_space(1))) void*)g,
      (__attribute__((address_space(3))) void*)l, 16, 0, 0);
}

// ---------------------------------------------------------------------------
// One-time input conversions
// ---------------------------------------------------------------------------
__global__ __launch_bounds__(256) void convert_f32_bf16(
    const float* __restrict__ src, ushort_t* __restrict__ dst) {
  int i = blockIdx.x * 256 + threadIdx.x;   // one float4 per thread
  float4 v = ((const float4*)src)[i];
  u16x4 o = {f2bf(v.x), f2bf(v.y), f2bf(v.z), f2bf(v.w)};
  ((u16x4*)dst)[i] = o;
}

// dst[n][k] = bf16(src[k][n]); src is [K][N] fp32
__global__ __launch_bounds__(256) void transpose_f32_bf16(
    const float* __restrict__ src, ushort_t* __restrict__ dst, int K, int N) {
  __shared__ float tile[32][33];
  int tx = threadIdx.x & 31, ty = threadIdx.x >> 5;   // 32 x 8
  int n0 = blockIdx.x * 32, k0 = blockIdx.y * 32;
#pragma unroll
  for (int i = 0; i < 4; i++) {
    int k = ty + i * 8;
    tile[k][tx] = src[(size_t)(k0 + k) * N + n0 + tx];
  }
  __syncthreads();
#pragma unroll
  for (int i = 0; i < 4; i++) {
    int r = ty + i * 8;
    dst[(size_t)(n0 + r) * K + k0 + tx] = f2bf(tile[tx][r]);
  }
}

// ---------------------------------------------------------------------------
// GEMM1 fused — 256x(128h+128g) tile, 8-wave, 4-phase/K-tile schedule with
// counted vmcnt (T2+T3+T4+T5). BK=64. LDS: A 3-deep halves (96K) + B 2-deep
// halves (64K) = 160 KB. XOR-swizzle slot^=(row&7) applied on BOTH the
// global source of global_load_lds and the ds_read address.
// Epilogue: (h,g) pairs are in-register -> lclv -> packed 2xbf16 to LCLV.
// ---------------------------------------------------------------------------
#define G1_BK 64
#define G1_NT (DIM / G1_BK)   // 16 K-tiles

__global__ __launch_bounds__(512, 2) void gemm1_fused(
    const ushort_t* __restrict__ Xbf, const ushort_t* __restrict__ Wt,
    unsigned int* __restrict__ LCLV) {
  // A slots: (buf3*2+half)*8192, buf3 in 0..2   -> 49152 ushorts
  // B slots: 49152 + (buf2*2+half)*8192, buf2 in 0..1 -> 32768 ushorts
  __shared__ __align__(16) ushort_t lds[81920];   // 160 KB exactly

  const int tid = threadIdx.x;
  const int wv = tid >> 6;
  const int lane = tid & 63;
  const int wr = wv >> 2;           // 0..1 (M half)
  const int wc = wv & 3;            // 0..3 (N quarter)
  const int l15 = lane & 15;
  const int quad = lane >> 4;
  const int n0 = blockIdx.x * 128;  // h-column base (g rows = +DIM_INNER in Wt)
  const int m0 = blockIdx.y * 256;

  floatx4 acc[8][4];
#pragma unroll
  for (int i = 0; i < 8; i++)
#pragma unroll
    for (int j = 0; j < 4; j++) acc[i][j] = (floatx4){0.f, 0.f, 0.f, 0.f};

  bf16x8 aF[4][2], bF[2][2];

  // stage one 128x64 half-tile (2 x 16B per thread), source pre-swizzled
  auto stageA = [&](int kt, int half, int buf) {
#pragma unroll
    for (int L = 0; L < 2; L++) {
      int e = L * 512 + tid;
      int row = e >> 3, slot = e & 7;
      const ushort_t* src = Xbf + (size_t)(m0 + half * 128 + row) * DIM +
                            kt * 64 + ((slot ^ (row & 7)) << 3);
      async_copy16(src, lds + (buf * 2 + half) * 8192 + e * 8);
    }
  };
  auto stageB = [&](int kt, int half, int buf) {
#pragma unroll
    for (int L = 0; L < 2; L++) {
      int e = L * 512 + tid;
      int row = e >> 3, slot = e & 7;
      int br = half * 128 + row;   // B-tile row 0..255
      // rows (br&63)<32 -> hidden col, else gate col (+DIM_INNER)
      int grow = n0 + ((br >> 6) << 5) + (br & 31) + ((br & 32) ? DIM_INNER : 0);
      const ushort_t* src = Wt + (size_t)grow * DIM +
                            kt * 64 + ((slot ^ (row & 7)) << 3);
      async_copy16(src, lds + 49152 + (buf * 2 + half) * 8192 + e * 8);
    }
  };
  auto readA = [&](int buf, int mf, int ks) -> bf16x8 {
    int r = mf * 16 + l15;
    const ushort_t* p = lds + (buf * 2 + wr) * 8192 + r * 64 +
                        ((((ks << 2) | quad) ^ (r & 7)) << 3);
    return __builtin_bit_cast(bf16x8, *(const short8_t*)p);
  };
  auto readB = [&](int buf, int nf, int ks) -> bf16x8 {
    int br = wc * 64 + nf * 16 + l15;     // nf 0,1 = h ; nf 2,3 = g (same cols)
    int half = br >> 7, r = br & 127;
    const ushort_t* p = lds + 49152 + (buf * 2 + half) * 8192 + r * 64 +
                        ((((ks << 2) | quad) ^ (r & 7)) << 3);
    return __builtin_bit_cast(bf16x8, *(const short8_t*)p);
  };
  auto mmaQ = [&](int mb, int nb) {
#pragma unroll
    for (int mf = 0; mf < 4; mf++)
#pragma unroll
      for (int nf = 0; nf < 2; nf++)
#pragma unroll
        for (int ks = 0; ks < 2; ks++)
          acc[mb + mf][nb + nf] = __builtin_amdgcn_mfma_f32_16x16x32_bf16(
              aF[mf][ks], bF[nf][ks], acc[mb + mf][nb + nf], 0, 0, 0);
  };

  // prologue: tile0 A+B, tile1 A; allow tile1's 4 A-loads outstanding
  stageA(0, 0, 0); stageA(0, 1, 0);
  stageB(0, 0, 0); stageB(0, 1, 0);
  stageA(1, 0, 1); stageA(1, 1, 1);
  asm volatile("s_waitcnt vmcnt(4)" ::: "memory");
  __builtin_amdgcn_s_barrier();

  int bufA = 0, bufB = 0, bufAn = 2, bufBn = 1;
  for (int u = 0; u < G1_NT; u++) {
    const int kb = (u + 1 < G1_NT) ? u + 1 : G1_NT - 1;   // B fetch tile
    const int ka = (u + 2 < G1_NT) ? u + 2 : G1_NT - 1;   // A fetch tile

    // ---- phase 0 : Q(mh0, nh0); stage B(u+1) half0
#pragma unroll
    for (int mf = 0; mf < 4; mf++)
#pragma unroll
      for (int ks = 0; ks < 2; ks++) aF[mf][ks] = readA(bufA, mf, ks);
#pragma unroll
    for (int nf = 0; nf < 2; nf++)
#pragma unroll
      for (int ks = 0; ks < 2; ks++) bF[nf][ks] = readB(bufB, nf, ks);
    stageB(kb, 0, bufBn);
    __builtin_amdgcn_s_barrier();
    asm volatile("s_waitcnt lgkmcnt(0)" ::: "memory");
    __builtin_amdgcn_sched_barrier(0);
    __builtin_amdgcn_s_setprio(1);
    mmaQ(0, 0);
    __builtin_amdgcn_s_setprio(0);
    __builtin_amdgcn_s_barrier();

    // ---- phase 1 : Q(mh0, nh1); stage B(u+1) half1
#pragma unroll
    for (int nf = 0; nf < 2; nf++)
#pragma unroll
      for (int ks = 0; ks < 2; ks++) bF[nf][ks] = readB(bufB, nf + 2, ks);
    stageB(kb, 1, bufBn);
    __builtin_amdgcn_s_barrier();
    asm volatile("s_waitcnt lgkmcnt(0)" ::: "memory");
    __builtin_amdgcn_sched_barrier(0);
    __builtin_amdgcn_s_setprio(1);
    mmaQ(0, 2);
    __builtin_amdgcn_s_setprio(0);
    __builtin_amdgcn_s_barrier();

    // ---- phase 2 : Q(mh1, nh1) (reuse bF); stage A(u+2) half0
#pragma unroll
    for (int mf = 0; mf < 4; mf++)
#pragma unroll
      for (int ks = 0; ks < 2; ks++) aF[mf][ks] = readA(bufA, mf + 4, ks);
    stageA(ka, 0, bufAn);
    __builtin_amdgcn_s_barrier();
    asm volatile("s_waitcnt lgkmcnt(0)" ::: "memory");
    __builtin_amdgcn_sched_barrier(0);
    __builtin_amdgcn_s_setprio(1);
    mmaQ(4, 2);
    __builtin_amdgcn_s_setprio(0);
    __builtin_amdgcn_s_barrier();

    // ---- phase 3 : Q(mh1, nh0); stage A(u+2) half1; counted vmcnt
#pragma unroll
    for (int nf = 0; nf < 2; nf++)
#pragma unroll
      for (int ks = 0; ks < 2; ks++) bF[nf][ks] = readB(bufB, nf, ks);
    stageA(ka, 1, bufAn);
    // allow the 4 A(u+2) loads (phases 2,3) in flight; everything older
    // (A(u+1), B(u+1)) is forced landed before tile u+1's reads.
    asm volatile("s_waitcnt vmcnt(4)" ::: "memory");
    __builtin_amdgcn_s_barrier();
    asm volatile("s_waitcnt lgkmcnt(0)" ::: "memory");
    __builtin_amdgcn_sched_barrier(0);
    __builtin_amdgcn_s_setprio(1);
    mmaQ(4, 0);
    __builtin_amdgcn_s_setprio(0);
    __builtin_amdgcn_s_barrier();

    bufA = (bufA == 2) ? 0 : bufA + 1;
    bufAn = (bufAn == 2) ? 0 : bufAn + 1;
    bufB ^= 1; bufBn ^= 1;
  }

  // epilogue: (h,g) pairs are acc[mf][j] / acc[mf][j+2], same (row,col)
#pragma unroll
  for (int mf = 0; mf < 8; mf++)
#pragma unroll
    for (int j = 0; j < 2; j++) {
      int col = n0 + wc * 32 + j * 16 + l15;
#pragma unroll
      for (int r = 0; r < 4; r++) {
        int row = m0 + wr * 128 + mf * 16 + quad * 4 + r;
        float lc, lv;
        lclv_fast(acc[mf][j][r], acc[mf][j + 2][r], lc, lv);
        unsigned int pk = ((unsigned int)f2bf(lv) << 16) | (unsigned int)f2bf(lc);
        LCLV[(size_t)row * DIM_INNER + col] = pk;
      }
    }
}

// ---------------------------------------------------------------------------
// Chunked log-space scan, 4 channels/thread, CHUNK=32 (262k threads @ nb=4)
// ---------------------------------------------------------------------------
__global__ __launch_bounds__(256) void scan_phase1(
    const unsigned int* __restrict__ LCLV,
    float* __restrict__ Asum, float* __restrict__ Lend, int nbch) {
  const int EQ = DIM_INNER / 4;               // 512 channel-quads per batch
  int tid = blockIdx.x * 256 + threadIdx.x;   // nb * EQ * NCHUNK
  int ep = tid % EQ;
  int tmp = tid / EQ;
  int c = tmp % NCHUNK;
  int bz = tmp / NCHUNK;
  size_t base4 = ((size_t)bz * SEQ + (size_t)c * CHUNK) * EQ + ep;
  const uint4_t* L4 = (const uint4_t*)LCLV;

  float4_t asum = {0.f, 0.f, 0.f, 0.f};
  float4_t logh = {-INFINITY, -INFINITY, -INFINITY, -INFINITY};
#pragma unroll 4
  for (int t = 0; t < CHUNK; t++) {
    uint4_t u = L4[base4 + (size_t)t * EQ];
#pragma unroll
    for (int k = 0; k < 4; k++) {
      float lc = bflo2f(u[k]), lv = bfhi2f(u[k]);
      asum[k] += lc;
      logh[k] = logaddexp_f(lc + logh[k], lv);
    }
  }
  size_t sidx = ((size_t)c * nbch + (size_t)bz * DIM_INNER) / 4 + ep;
  ((float4_t*)Asum)[sidx] = asum;
  ((float4_t*)Lend)[sidx] = logh;
}

// In-place: Asum[c][ch] -> P[c][ch] (prefix BEFORE chunk c)
__global__ __launch_bounds__(256) void scan_phase2(
    float* Asum, const float* __restrict__ Lend, int nbch) {
  int ch = blockIdx.x * 256 + threadIdx.x;
  float p = -INFINITY;
  for (int c = 0; c < NCHUNK; c++) {
    float a = Asum[(size_t)c * nbch + ch];
    float le = Lend[(size_t)c * nbch + ch];
    Asum[(size_t)c * nbch + ch] = p;
    p = logaddexp_f(a + p, le);
  }
}

// Rescan with real prefix; write h = exp(log_h) as bf16 into H (8B/lane).
__global__ __launch_bounds__(256) void scan_phase3(
    const unsigned int* __restrict__ LCLV, const float* __restrict__ P,
    ushort_t* __restrict__ H, int nbch) {
  const int EQ = DIM_INNER / 4;
  int tid = blockIdx.x * 256 + threadIdx.x;
  int ep = tid % EQ;
  int tmp = tid / EQ;
  int c = tmp % NCHUNK;
  int bz = tmp / NCHUNK;
  size_t base4 = ((size_t)bz * SEQ + (size_t)c * CHUNK) * EQ + ep;
  const uint4_t* L4 = (const uint4_t*)LCLV;
  u16x4* H4 = (u16x4*)H;

  size_t pidx = ((size_t)c * nbch + (size_t)bz * DIM_INNER) / 4 + ep;
  float4_t logh = ((const float4_t*)P)[pidx];
#pragma unroll 4
  for (int t = 0; t < CHUNK; t++) {
    uint4_t u = L4[base4 + (size_t)t * EQ];
    u16x4 hv;
#pragma unroll
    for (int k = 0; k < 4; k++) {
      float lc = bflo2f(u[k]), lv = bfhi2f(u[k]);
      logh[k] = logaddexp_f(lc + logh[k], lv);
      hv[k] = f2bf(__expf(logh[k]));
    }
    H4[base4 + (size_t)t * EQ] = hv;
  }
}

// ---------------------------------------------------------------------------
// GEMM2 (m97 structure): out = H @ W_out.
// ---------------------------------------------------------------------------
__global__ __launch_bounds__(256) void gemm2(
    const ushort_t* __restrict__ Hbf, const ushort_t* __restrict__ Wot,
    float* __restrict__ OUT) {
  __shared__ __align__(16) ushort_t As[128 * 32];
  __shared__ __align__(16) ushort_t Bs[128 * 32];

  const int tid = threadIdx.x;
  const int wave = tid >> 6;
  const int lane = tid & 63;
  const int n0 = blockIdx.x * 128;
  const int m0 = blockIdx.y * 128;
  const int l15 = lane & 15;
  const int quad = lane >> 4;
  const int wr = wave >> 1, wc = wave & 1;
  const int lrow = lane >> 2;
  const int lkof = (lane & 3) * 8;

  floatx4 acc[4][4];
#pragma unroll
  for (int i = 0; i < 4; i++)
#pragma unroll
    for (int j = 0; j < 4; j++) acc[i][j] = (floatx4){0.f, 0.f, 0.f, 0.f};

  for (int k0 = 0; k0 < DIM_INNER; k0 += 32) {
    __syncthreads();
#pragma unroll
    for (int p = 0; p < 2; p++) {
      int u = wave + p * 4;
      async_copy16(Hbf + (size_t)(m0 + u * 16 + lrow) * DIM_INNER + k0 + lkof,
                   As + u * 512);
      async_copy16(Wot + (size_t)(n0 + u * 16 + lrow) * DIM_INNER + k0 + lkof,
                   Bs + u * 512);
    }
    __syncthreads();

    bf16x8 af[4], bf[4];
#pragma unroll
    for (int i = 0; i < 4; i++) {
      short8_t sa = *(const short8_t*)(As + (size_t)(wr * 64 + i * 16 + l15) * 32 + quad * 8);
      af[i] = __builtin_bit_cast(bf16x8, sa);
      short8_t sb = *(const short8_t*)(Bs + (size_t)(wc * 64 + i * 16 + l15) * 32 + quad * 8);
      bf[i] = __builtin_bit_cast(bf16x8, sb);
    }
#pragma unroll
    for (int i = 0; i < 4; i++)
#pragma unroll
      for (int j = 0; j < 4; j++)
        acc[i][j] = __builtin_amdgcn_mfma_f32_16x16x32_bf16(af[i], bf[j], acc[i][j], 0, 0, 0);
  }

#pragma unroll
  for (int i = 0; i < 4; i++)
#pragma unroll
    for (int j = 0; j < 4; j++) {
      int col = n0 + wc * 64 + j * 16 + l15;
#pragma unroll
      for (int r = 0; r < 4; r++) {
        int row = m0 + wr * 64 + i * 16 + quad * 4 + r;
        OUT[(size_t)row * DIM + col] = acc[i][j][r];
      }
    }
}

extern "C" void kernel_launch(void* const* d_in, const int* in_sizes, int n_in,
                              void* d_out, int out_size, void* d_ws, size_t ws_size,
                              hipStream_t stream) {
  const float* X = (const float*)d_in[0];     // [4,4096,1024]
  const float* Whg = (const float*)d_in[1];   // [1024,4096]
  const float* Wout = (const float*)d_in[2];  // [2048,1024]
  float* out = (float*)d_out;                 // [4,4096,1024] fp32

  ushort_t* Xbf = (ushort_t*)d_ws;
  ushort_t* Whg_t = Xbf + (size_t)MTOT * DIM;                   // [4096][1024]
  ushort_t* Wout_t = Whg_t + (size_t)(2 * DIM_INNER) * DIM;     // [1024][2048]
  char* pp = (char*)(Wout_t + (size_t)DIM * DIM_INNER);

  const size_t fixed_bytes = (size_t)MTOT * DIM * 2 +
                             (size_t)2 * DIM_INNER * DIM * 2 +
                             (size_t)DIM * DIM_INNER * 2;
  // per batch: LCLV 4B + H 2B per elem + 2 summaries
  const size_t per_batch = (size_t)SEQ * DIM_INNER * 4 +
                           (size_t)SEQ * DIM_INNER * 2 +
                           2 * (size_t)DIM_INNER * NCHUNK * 4;
  int nb = 4;
  while (nb > 1 && fixed_bytes + (size_t)nb * per_batch > ws_size) nb >>= 1;
  const int npass = BATCH / nb;

  convert_f32_bf16<<<(MTOT * DIM / 4) / 256, 256, 0, stream>>>(X, Xbf);
  transpose_f32_bf16<<<dim3(2 * DIM_INNER / 32, DIM / 32), 256, 0, stream>>>(
      Whg, Whg_t, DIM, 2 * DIM_INNER);
  transpose_f32_bf16<<<dim3(DIM / 32, DIM_INNER / 32), 256, 0, stream>>>(
      Wout, Wout_t, DIM_INNER, DIM);

  for (int pass = 0; pass < npass; pass++) {
    const int b0 = pass * nb;
    const int nrows = nb * SEQ;
    const int nbch = nb * DIM_INNER;

    unsigned int* LCLV = (unsigned int*)pp;
    ushort_t* Hbf = (ushort_t*)(LCLV + (size_t)nb * SEQ * DIM_INNER);
    float* Asum = (float*)(Hbf + (size_t)nb * SEQ * DIM_INNER);
    float* Lend = Asum + (size_t)nb * DIM_INNER * NCHUNK;

    gemm1_fused<<<dim3(DIM_INNER / 128, nrows / 256), 512, 0, stream>>>(
        Xbf + (size_t)b0 * SEQ * DIM, Whg_t, LCLV);
    scan_phase1<<<(nbch / 4 * NCHUNK) / 256, 256, 0, stream>>>(LCLV, Asum, Lend, nbch);
    scan_phase2<<<nbch / 256, 256, 0, stream>>>(Asum, Lend, nbch);
    scan_phase3<<<(nbch / 4 * NCHUNK) / 256, 256, 0, stream>>>(LCLV, Asum, Hbf, nbch);
    gemm2<<<dim3(DIM / 128, nrows / 128), 256, 0, stream>>>(
        Hbf, Wout_t, out + (size_t)b0 * SEQ * DIM);
  }
}

// Round 2
// 425.144 us; speedup vs baseline: 1.1959x; 1.1595x over previous
//
#include <hip/hip_runtime.h>
#include <cmath>

#define DIM 1024
#define DIM_INNER 2048
#define BATCH 4
#define SEQ 4096
#define MTOT (BATCH * SEQ)
#define CHUNK 32
#define NCHUNK (SEQ / CHUNK)        // 128 chunks per sequence

typedef __bf16 bf16x8 __attribute__((ext_vector_type(8)));
typedef short short8_t __attribute__((ext_vector_type(8)));
typedef float floatx4 __attribute__((ext_vector_type(4)));
typedef unsigned short u16x4 __attribute__((ext_vector_type(4)));
typedef unsigned int uint4_t __attribute__((ext_vector_type(4)));
typedef float float4_t __attribute__((ext_vector_type(4)));
typedef unsigned short ushort_t;

template <int N> struct IC { static constexpr int v = N; };
template <bool B> struct BC { static constexpr bool v = B; };

#define LGKM_SB(n) do { asm volatile("s_waitcnt lgkmcnt(" #n ")" ::: "memory"); \
                        __builtin_amdgcn_sched_barrier(0); } while (0)
#define SCHED0() __builtin_amdgcn_sched_barrier(0)
#define SBAR() __builtin_amdgcn_s_barrier()

__device__ __forceinline__ unsigned short f2bf(float f) {
  unsigned int u = __builtin_bit_cast(unsigned int, f);
  u += 0x7fffu + ((u >> 16) & 1u);   // round-to-nearest-even
  return (unsigned short)(u >> 16);
}
__device__ __forceinline__ float bflo2f(unsigned int u) {
  return __builtin_bit_cast(float, u << 16);
}
__device__ __forceinline__ float bfhi2f(unsigned int u) {
  return __builtin_bit_cast(float, u & 0xffff0000u);
}

// Fast (native v_exp/v_log) log-space terms from (h, g):
//   lc = -softplus(g) ;  lv = -softplus(-g) + log_g(h) = g + lc + log_g(h)
__device__ __forceinline__ void lclv_fast(float h, float g, float& lc, float& lv) {
  float eg = __expf(-fabsf(g));
  float sp = fmaxf(g, 0.f) + __logf(1.f + eg);
  lc = -sp;
  float eh = __expf(h);
  float t  = (h >= 0.f) ? (h + 0.5f) : (1.f + eh);
  float lt = __logf(t);
  float lg = (h >= 0.f) ? lt : (h - lt);
  lv = g + lc + lg;
}
// a may be -inf; b finite
__device__ __forceinline__ float logaddexp_f(float a, float b) {
  float m = fmaxf(a, b);
  return m + __logf(1.f + __expf(-fabsf(a - b)));
}

// async 16B/lane global->LDS; dest = wave-uniform base + lane*16
__device__ __forceinline__ void async_copy16(const ushort_t* g, ushort_t* l) {
  __builtin_amdgcn_global_load_lds(
      (const __attribute__((address_space(1))) void*)g,
      (__attribute__((address_space(3))) void*)l, 16, 0, 0);
}

// ---------------------------------------------------------------------------
// One-time input conversions
// ---------------------------------------------------------------------------
__global__ __launch_bounds__(256) void convert_f32_bf16(
    const float* __restrict__ src, ushort_t* __restrict__ dst) {
  int i = blockIdx.x * 256 + threadIdx.x;   // one float4 per thread
  float4 v = ((const float4*)src)[i];
  u16x4 o = {f2bf(v.x), f2bf(v.y), f2bf(v.z), f2bf(v.w)};
  ((u16x4*)dst)[i] = o;
}

// dst[n][k] = bf16(src[k][n]); src is [K][N] fp32
__global__ __launch_bounds__(256) void transpose_f32_bf16(
    const float* __restrict__ src, ushort_t* __restrict__ dst, int K, int N) {
  __shared__ float tile[32][33];
  int tx = threadIdx.x & 31, ty = threadIdx.x >> 5;   // 32 x 8
  int n0 = blockIdx.x * 32, k0 = blockIdx.y * 32;
#pragma unroll
  for (int i = 0; i < 4; i++) {
    int k = ty + i * 8;
    tile[k][tx] = src[(size_t)(k0 + k) * N + n0 + tx];
  }
  __syncthreads();
#pragma unroll
  for (int i = 0; i < 4; i++) {
    int r = ty + i * 8;
    dst[(size_t)(n0 + r) * K + k0 + tx] = f2bf(tile[tx][r]);
  }
}

// ---------------------------------------------------------------------------
// GEMM1 fused — 256x(128h+128g), 8-wave, 4 phases/K-tile, BK=64.
// LDS: A triple-buffered halves (96K) + B double-buffered halves (64K).
// Schedule: per phase, ds_reads issued in pinned groups; after the barrier,
// counted lgkmcnt interleaves MFMA groups with outstanding LDS reads so the
// LDS drain overlaps the matrix pipe. B fragments for the whole K-tile are
// held in registers (read once); phase 3 is read-free and carries the
// counted vmcnt(4). Last two K-tiles are peeled (keeps kt affine -> address
// strength reduction; tail uses vmcnt(0)).
// ---------------------------------------------------------------------------
#define G1_NT (DIM / 64)        // 16 K-tiles
#define G2_NT (DIM_INNER / 64)  // 32 K-tiles

__global__ __launch_bounds__(512, 2) void gemm1_fused(
    const ushort_t* __restrict__ Xbf, const ushort_t* __restrict__ Wt,
    unsigned int* __restrict__ LCLV) {
  __shared__ __align__(16) ushort_t lds[81920];   // 160 KB exactly

  const int tid = threadIdx.x;
  const int wv = tid >> 6;
  const int lane = tid & 63;
  const int wr = wv >> 2;           // 0..1 (M half)
  const int wc = wv & 3;            // 0..3 (N quarter)
  const int l15 = lane & 15;
  const int quad = lane >> 4;
  const int n0 = blockIdx.x * 128;  // h-column base (g rows = +DIM_INNER in Wt)
  const int m0 = blockIdx.y * 256;

  // ---- precomputed staging offsets (32-bit; exclude kt*64 which is affine)
  int aSrc[2][2], bSrc[2][2];   // [half][L]
  int dstE[2];
#pragma unroll
  for (int L = 0; L < 2; L++) {
    int e = L * 512 + tid;
    int row = e >> 3, slot = e & 7;
    int sw = (slot ^ (row & 7)) << 3;
    dstE[L] = e * 8;
#pragma unroll
    for (int half = 0; half < 2; half++) {
      aSrc[half][L] = (m0 + half * 128 + row) * DIM + sw;
      int br = half * 128 + row;
      int grow = n0 + ((br >> 6) << 5) + (br & 31) + ((br & 32) ? DIM_INNER : 0);
      bSrc[half][L] = grow * DIM + sw;
    }
  }

  auto stageA = [&](int kt, int half, int buf) {
#pragma unroll
    for (int L = 0; L < 2; L++)
      async_copy16(Xbf + aSrc[half][L] + kt * 64,
                   lds + buf * 16384 + half * 8192 + dstE[L]);
  };
  auto stageB = [&](int kt, int half, int buf) {
#pragma unroll
    for (int L = 0; L < 2; L++)
      async_copy16(Wt + bSrc[half][L] + kt * 64,
                   lds + 49152 + buf * 16384 + half * 8192 + dstE[L]);
  };

  // ---- precomputed ds_read bases (swz depends only on ks,quad,l15&7)
  const int swz0 = ((quad ^ (l15 & 7)) << 3);
  const int swz1 = (((4 | quad) ^ (l15 & 7)) << 3);
  const int aB0 = wr * 8192 + l15 * 64 + swz0;
  const int aB1 = wr * 8192 + l15 * 64 + swz1;
  const int bB0 = wc * 4096 + l15 * 64 + swz0;
  const int bB1 = wc * 4096 + l15 * 64 + swz1;

  auto readA = [&](int buf, int mf, int ks) -> bf16x8 {
    const ushort_t* p = lds + buf * 16384 + (ks ? aB1 : aB0) + mf * 1024;
    return __builtin_bit_cast(bf16x8, *(const short8_t*)p);
  };
  auto readB = [&](int buf, int nf, int ks) -> bf16x8 {
    const ushort_t* p = lds + 49152 + buf * 16384 + (ks ? bB1 : bB0) + nf * 1024;
    return __builtin_bit_cast(bf16x8, *(const short8_t*)p);
  };

  floatx4 acc[8][4];
#pragma unroll
  for (int i = 0; i < 8; i++)
#pragma unroll
    for (int j = 0; j < 4; j++) acc[i][j] = (floatx4){0.f, 0.f, 0.f, 0.f};

  bf16x8 aF[4][2], b0F[2][2], b1F[2][2];

  // 4 MFMA: aF[MA] x bX[0..1] -> acc[MC][J], acc[MC][J+1]
  auto mma4 = [&](auto MA, auto MC, auto J, bf16x8 (&bX)[2][2]) {
#pragma unroll
    for (int jj = 0; jj < 2; jj++)
#pragma unroll
      for (int ks = 0; ks < 2; ks++)
        acc[MC.v][J.v + jj] = __builtin_amdgcn_mfma_f32_16x16x32_bf16(
            aF[MA.v][ks], bX[jj][ks], acc[MC.v][J.v + jj], 0, 0, 0);
  };
  // 8 MFMA: aF[0..3] x bvec -> acc[0..3][J]
  auto mmaRow = [&](auto J, bf16x8 (&bvec)[2]) {
#pragma unroll
    for (int m = 0; m < 4; m++)
#pragma unroll
      for (int ks = 0; ks < 2; ks++)
        acc[m][J.v] = __builtin_amdgcn_mfma_f32_16x16x32_bf16(
            aF[m][ks], bvec[ks], acc[m][J.v], 0, 0, 0);
  };

  int bufA = 0, bufB = 0, bufAn = 2, bufBn = 1;

  auto tileBody = [&](int kb, int ka, auto STB, auto STA, auto VMALL) {
    // ---------- phase 0 : Q(mh0 x nh0); stage B(kb) half0
    aF[0][0] = readA(bufA, 0, 0); aF[0][1] = readA(bufA, 0, 1);
    b0F[0][0] = readB(bufB, 0, 0); b0F[0][1] = readB(bufB, 0, 1);
    b0F[1][0] = readB(bufB, 1, 0); b0F[1][1] = readB(bufB, 1, 1);
    SCHED0();
    aF[1][0] = readA(bufA, 1, 0); aF[1][1] = readA(bufA, 1, 1);
    SCHED0();
    aF[2][0] = readA(bufA, 2, 0); aF[2][1] = readA(bufA, 2, 1);
    SCHED0();
    aF[3][0] = readA(bufA, 3, 0); aF[3][1] = readA(bufA, 3, 1);
    SCHED0();
    if constexpr (STB.v) stageB(kb, 0, bufBn);
    SBAR();
    __builtin_amdgcn_s_setprio(1);
    LGKM_SB(6); mma4(IC<0>{}, IC<0>{}, IC<0>{}, b0F);
    LGKM_SB(4); mma4(IC<1>{}, IC<1>{}, IC<0>{}, b0F);
    LGKM_SB(2); mma4(IC<2>{}, IC<2>{}, IC<0>{}, b0F);
    LGKM_SB(0); mma4(IC<3>{}, IC<3>{}, IC<0>{}, b0F);
    __builtin_amdgcn_s_setprio(0);
    SBAR();

    // ---------- phase 1 : Q(mh0 x nh1); stage B(kb) half1
    b1F[0][0] = readB(bufB, 2, 0); b1F[0][1] = readB(bufB, 2, 1);
    SCHED0();
    b1F[1][0] = readB(bufB, 3, 0); b1F[1][1] = readB(bufB, 3, 1);
    SCHED0();
    if constexpr (STB.v) stageB(kb, 1, bufBn);
    SBAR();
    __builtin_amdgcn_s_setprio(1);
    LGKM_SB(2); mmaRow(IC<2>{}, b1F[0]);
    LGKM_SB(0); mmaRow(IC<3>{}, b1F[1]);
    __builtin_amdgcn_s_setprio(0);
    SBAR();

    // ---------- phase 2 : Q(mh1 x nh1); stage A(ka) half0
    aF[0][0] = readA(bufA, 4, 0); aF[0][1] = readA(bufA, 4, 1);
    SCHED0();
    aF[1][0] = readA(bufA, 5, 0); aF[1][1] = readA(bufA, 5, 1);
    SCHED0();
    aF[2][0] = readA(bufA, 6, 0); aF[2][1] = readA(bufA, 6, 1);
    SCHED0();
    aF[3][0] = readA(bufA, 7, 0); aF[3][1] = readA(bufA, 7, 1);
    SCHED0();
    if constexpr (STA.v) stageA(ka, 0, bufAn);
    SBAR();
    __builtin_amdgcn_s_setprio(1);
    LGKM_SB(6); mma4(IC<0>{}, IC<4>{}, IC<2>{}, b1F);
    LGKM_SB(4); mma4(IC<1>{}, IC<5>{}, IC<2>{}, b1F);
    LGKM_SB(2); mma4(IC<2>{}, IC<6>{}, IC<2>{}, b1F);
    LGKM_SB(0); mma4(IC<3>{}, IC<7>{}, IC<2>{}, b1F);
    __builtin_amdgcn_s_setprio(0);
    SBAR();

    // ---------- phase 3 : Q(mh1 x nh0); stage A(ka) half1; counted vmcnt
    if constexpr (STA.v) stageA(ka, 1, bufAn);
    SCHED0();
    if constexpr (STA.v) {
      asm volatile("s_waitcnt vmcnt(4)" ::: "memory");
    } else if constexpr (VMALL.v) {
      asm volatile("s_waitcnt vmcnt(0)" ::: "memory");
    }
    SBAR();
    __builtin_amdgcn_s_setprio(1);
    mma4(IC<0>{}, IC<4>{}, IC<0>{}, b0F);
    mma4(IC<1>{}, IC<5>{}, IC<0>{}, b0F);
    mma4(IC<2>{}, IC<6>{}, IC<0>{}, b0F);
    mma4(IC<3>{}, IC<7>{}, IC<0>{}, b0F);
    __builtin_amdgcn_s_setprio(0);
    SBAR();
  };

  // prologue: B(0), A(0), A(1); keep A(1)'s 4 loads in flight
  stageB(0, 0, 0); stageB(0, 1, 0);
  stageA(0, 0, 0); stageA(0, 1, 0);
  stageA(1, 0, 1); stageA(1, 1, 1);
  asm volatile("s_waitcnt vmcnt(4)" ::: "memory");
  SBAR();

  for (int u = 0; u < G1_NT - 2; u++) {
    tileBody(u + 1, u + 2, BC<true>{}, BC<true>{}, BC<false>{});
    bufA = (bufA == 2) ? 0 : bufA + 1;
    bufAn = (bufAn == 2) ? 0 : bufAn + 1;
    bufB ^= 1; bufBn ^= 1;
  }
  tileBody(G1_NT - 1, 0, BC<true>{}, BC<false>{}, BC<true>{});
  bufA = (bufA == 2) ? 0 : bufA + 1;
  bufB ^= 1;
  tileBody(0, 0, BC<false>{}, BC<false>{}, BC<false>{});

  // epilogue: (h,g) pairs are acc[mf][j] / acc[mf][j+2], same (row,col)
#pragma unroll
  for (int mf = 0; mf < 8; mf++)
#pragma unroll
    for (int j = 0; j < 2; j++) {
      int col = n0 + wc * 32 + j * 16 + l15;
#pragma unroll
      for (int r = 0; r < 4; r++) {
        int row = m0 + wr * 128 + mf * 16 + quad * 4 + r;
        float lc, lv;
        lclv_fast(acc[mf][j][r], acc[mf][j + 2][r], lc, lv);
        unsigned int pk = ((unsigned int)f2bf(lv) << 16) | (unsigned int)f2bf(lc);
        LCLV[(size_t)row * DIM_INNER + col] = pk;
      }
    }
}

// ---------------------------------------------------------------------------
// GEMM2 — same 256x256 template: out = H @ W_out, K = 2048 (32 tiles).
// grid = (DIM/256) x (rows/256) = 256 blocks -> exactly 1 per CU.
// ---------------------------------------------------------------------------
__global__ __launch_bounds__(512, 2) void gemm2(
    const ushort_t* __restrict__ Hbf, const ushort_t* __restrict__ Wot,
    float* __restrict__ OUT) {
  __shared__ __align__(16) ushort_t lds[81920];

  const int tid = threadIdx.x;
  const int wv = tid >> 6;
  const int lane = tid & 63;
  const int wr = wv >> 2;
  const int wc = wv & 3;
  const int l15 = lane & 15;
  const int quad = lane >> 4;
  const int n0 = blockIdx.x * 256;
  const int m0 = blockIdx.y * 256;

  int aSrc[2][2], bSrc[2][2];
  int dstE[2];
#pragma unroll
  for (int L = 0; L < 2; L++) {
    int e = L * 512 + tid;
    int row = e >> 3, slot = e & 7;
    int sw = (slot ^ (row & 7)) << 3;
    dstE[L] = e * 8;
#pragma unroll
    for (int half = 0; half < 2; half++) {
      aSrc[half][L] = (m0 + half * 128 + row) * DIM_INNER + sw;
      bSrc[half][L] = (n0 + half * 128 + row) * DIM_INNER + sw;
    }
  }

  auto stageA = [&](int kt, int half, int buf) {
#pragma unroll
    for (int L = 0; L < 2; L++)
      async_copy16(Hbf + aSrc[half][L] + kt * 64,
                   lds + buf * 16384 + half * 8192 + dstE[L]);
  };
  auto stageB = [&](int kt, int half, int buf) {
#pragma unroll
    for (int L = 0; L < 2; L++)
      async_copy16(Wot + bSrc[half][L] + kt * 64,
                   lds + 49152 + buf * 16384 + half * 8192 + dstE[L]);
  };

  const int swz0 = ((quad ^ (l15 & 7)) << 3);
  const int swz1 = (((4 | quad) ^ (l15 & 7)) << 3);
  const int aB0 = wr * 8192 + l15 * 64 + swz0;
  const int aB1 = wr * 8192 + l15 * 64 + swz1;
  const int bB0 = wc * 4096 + l15 * 64 + swz0;
  const int bB1 = wc * 4096 + l15 * 64 + swz1;

  auto readA = [&](int buf, int mf, int ks) -> bf16x8 {
    const ushort_t* p = lds + buf * 16384 + (ks ? aB1 : aB0) + mf * 1024;
    return __builtin_bit_cast(bf16x8, *(const short8_t*)p);
  };
  auto readB = [&](int buf, int nf, int ks) -> bf16x8 {
    const ushort_t* p = lds + 49152 + buf * 16384 + (ks ? bB1 : bB0) + nf * 1024;
    return __builtin_bit_cast(bf16x8, *(const short8_t*)p);
  };

  floatx4 acc[8][4];
#pragma unroll
  for (int i = 0; i < 8; i++)
#pragma unroll
    for (int j = 0; j < 4; j++) acc[i][j] = (floatx4){0.f, 0.f, 0.f, 0.f};

  bf16x8 aF[4][2], b0F[2][2], b1F[2][2];

  auto mma4 = [&](auto MA, auto MC, auto J, bf16x8 (&bX)[2][2]) {
#pragma unroll
    for (int jj = 0; jj < 2; jj++)
#pragma unroll
      for (int ks = 0; ks < 2; ks++)
        acc[MC.v][J.v + jj] = __builtin_amdgcn_mfma_f32_16x16x32_bf16(
            aF[MA.v][ks], bX[jj][ks], acc[MC.v][J.v + jj], 0, 0, 0);
  };
  auto mmaRow = [&](auto J, bf16x8 (&bvec)[2]) {
#pragma unroll
    for (int m = 0; m < 4; m++)
#pragma unroll
      for (int ks = 0; ks < 2; ks++)
        acc[m][J.v] = __builtin_amdgcn_mfma_f32_16x16x32_bf16(
            aF[m][ks], bvec[ks], acc[m][J.v], 0, 0, 0);
  };

  int bufA = 0, bufB = 0, bufAn = 2, bufBn = 1;

  auto tileBody = [&](int kb, int ka, auto STB, auto STA, auto VMALL) {
    aF[0][0] = readA(bufA, 0, 0); aF[0][1] = readA(bufA, 0, 1);
    b0F[0][0] = readB(bufB, 0, 0); b0F[0][1] = readB(bufB, 0, 1);
    b0F[1][0] = readB(bufB, 1, 0); b0F[1][1] = readB(bufB, 1, 1);
    SCHED0();
    aF[1][0] = readA(bufA, 1, 0); aF[1][1] = readA(bufA, 1, 1);
    SCHED0();
    aF[2][0] = readA(bufA, 2, 0); aF[2][1] = readA(bufA, 2, 1);
    SCHED0();
    aF[3][0] = readA(bufA, 3, 0); aF[3][1] = readA(bufA, 3, 1);
    SCHED0();
    if constexpr (STB.v) stageB(kb, 0, bufBn);
    SBAR();
    __builtin_amdgcn_s_setprio(1);
    LGKM_SB(6); mma4(IC<0>{}, IC<0>{}, IC<0>{}, b0F);
    LGKM_SB(4); mma4(IC<1>{}, IC<1>{}, IC<0>{}, b0F);
    LGKM_SB(2); mma4(IC<2>{}, IC<2>{}, IC<0>{}, b0F);
    LGKM_SB(0); mma4(IC<3>{}, IC<3>{}, IC<0>{}, b0F);
    __builtin_amdgcn_s_setprio(0);
    SBAR();

    b1F[0][0] = readB(bufB, 2, 0); b1F[0][1] = readB(bufB, 2, 1);
    SCHED0();
    b1F[1][0] = readB(bufB, 3, 0); b1F[1][1] = readB(bufB, 3, 1);
    SCHED0();
    if constexpr (STB.v) stageB(kb, 1, bufBn);
    SBAR();
    __builtin_amdgcn_s_setprio(1);
    LGKM_SB(2); mmaRow(IC<2>{}, b1F[0]);
    LGKM_SB(0); mmaRow(IC<3>{}, b1F[1]);
    __builtin_amdgcn_s_setprio(0);
    SBAR();

    aF[0][0] = readA(bufA, 4, 0); aF[0][1] = readA(bufA, 4, 1);
    SCHED0();
    aF[1][0] = readA(bufA, 5, 0); aF[1][1] = readA(bufA, 5, 1);
    SCHED0();
    aF[2][0] = readA(bufA, 6, 0); aF[2][1] = readA(bufA, 6, 1);
    SCHED0();
    aF[3][0] = readA(bufA, 7, 0); aF[3][1] = readA(bufA, 7, 1);
    SCHED0();
    if constexpr (STA.v) stageA(ka, 0, bufAn);
    SBAR();
    __builtin_amdgcn_s_setprio(1);
    LGKM_SB(6); mma4(IC<0>{}, IC<4>{}, IC<2>{}, b1F);
    LGKM_SB(4); mma4(IC<1>{}, IC<5>{}, IC<2>{}, b1F);
    LGKM_SB(2); mma4(IC<2>{}, IC<6>{}, IC<2>{}, b1F);
    LGKM_SB(0); mma4(IC<3>{}, IC<7>{}, IC<2>{}, b1F);
    __builtin_amdgcn_s_setprio(0);
    SBAR();

    if constexpr (STA.v) stageA(ka, 1, bufAn);
    SCHED0();
    if constexpr (STA.v) {
      asm volatile("s_waitcnt vmcnt(4)" ::: "memory");
    } else if constexpr (VMALL.v) {
      asm volatile("s_waitcnt vmcnt(0)" ::: "memory");
    }
    SBAR();
    __builtin_amdgcn_s_setprio(1);
    mma4(IC<0>{}, IC<4>{}, IC<0>{}, b0F);
    mma4(IC<1>{}, IC<5>{}, IC<0>{}, b0F);
    mma4(IC<2>{}, IC<6>{}, IC<0>{}, b0F);
    mma4(IC<3>{}, IC<7>{}, IC<0>{}, b0F);
    __builtin_amdgcn_s_setprio(0);
    SBAR();
  };

  stageB(0, 0, 0); stageB(0, 1, 0);
  stageA(0, 0, 0); stageA(0, 1, 0);
  stageA(1, 0, 1); stageA(1, 1, 1);
  asm volatile("s_waitcnt vmcnt(4)" ::: "memory");
  SBAR();

  for (int u = 0; u < G2_NT - 2; u++) {
    tileBody(u + 1, u + 2, BC<true>{}, BC<true>{}, BC<false>{});
    bufA = (bufA == 2) ? 0 : bufA + 1;
    bufAn = (bufAn == 2) ? 0 : bufAn + 1;
    bufB ^= 1; bufBn ^= 1;
  }
  tileBody(G2_NT - 1, 0, BC<true>{}, BC<false>{}, BC<true>{});
  bufA = (bufA == 2) ? 0 : bufA + 1;
  bufB ^= 1;
  tileBody(0, 0, BC<false>{}, BC<false>{}, BC<false>{});

#pragma unroll
  for (int mf = 0; mf < 8; mf++)
#pragma unroll
    for (int j = 0; j < 4; j++) {
      int col = n0 + wc * 64 + (j >> 1) * 32 + (j & 1) * 16 + l15;
#pragma unroll
      for (int r = 0; r < 4; r++) {
        int row = m0 + wr * 128 + mf * 16 + quad * 4 + r;
        OUT[(size_t)row * DIM + col] = acc[mf][j][r];
      }
    }
}

// ---------------------------------------------------------------------------
// Chunked log-space scan, 4 channels/thread, CHUNK=32
// ---------------------------------------------------------------------------
__global__ __launch_bounds__(256) void scan_phase1(
    const unsigned int* __restrict__ LCLV,
    float* __restrict__ Asum, float* __restrict__ Lend, int nbch) {
  const int EQ = DIM_INNER / 4;               // 512 channel-quads per batch
  int tid = blockIdx.x * 256 + threadIdx.x;   // nb * EQ * NCHUNK
  int ep = tid % EQ;
  int tmp = tid / EQ;
  int c = tmp % NCHUNK;
  int bz = tmp / NCHUNK;
  size_t base4 = ((size_t)bz * SEQ + (size_t)c * CHUNK) * EQ + ep;
  const uint4_t* L4 = (const uint4_t*)LCLV;

  float4_t asum = {0.f, 0.f, 0.f, 0.f};
  float4_t logh = {-INFINITY, -INFINITY, -INFINITY, -INFINITY};
#pragma unroll 4
  for (int t = 0; t < CHUNK; t++) {
    uint4_t u = L4[base4 + (size_t)t * EQ];
#pragma unroll
    for (int k = 0; k < 4; k++) {
      float lc = bflo2f(u[k]), lv = bfhi2f(u[k]);
      asum[k] += lc;
      logh[k] = logaddexp_f(lc + logh[k], lv);
    }
  }
  size_t sidx = ((size_t)c * nbch + (size_t)bz * DIM_INNER) / 4 + ep;
  ((float4_t*)Asum)[sidx] = asum;
  ((float4_t*)Lend)[sidx] = logh;
}

// In-place: Asum[c][ch] -> P[c][ch] (prefix BEFORE chunk c)
__global__ __launch_bounds__(256) void scan_phase2(
    float* Asum, const float* __restrict__ Lend, int nbch) {
  int ch = blockIdx.x * 256 + threadIdx.x;
  float p = -INFINITY;
  for (int c = 0; c < NCHUNK; c++) {
    float a = Asum[(size_t)c * nbch + ch];
    float le = Lend[(size_t)c * nbch + ch];
    Asum[(size_t)c * nbch + ch] = p;
    p = logaddexp_f(a + p, le);
  }
}

// Rescan with real prefix; write h = exp(log_h) as bf16 into H (8B/lane).
__global__ __launch_bounds__(256) void scan_phase3(
    const unsigned int* __restrict__ LCLV, const float* __restrict__ P,
    ushort_t* __restrict__ H, int nbch) {
  const int EQ = DIM_INNER / 4;
  int tid = blockIdx.x * 256 + threadIdx.x;
  int ep = tid % EQ;
  int tmp = tid / EQ;
  int c = tmp % NCHUNK;
  int bz = tmp / NCHUNK;
  size_t base4 = ((size_t)bz * SEQ + (size_t)c * CHUNK) * EQ + ep;
  const uint4_t* L4 = (const uint4_t*)LCLV;
  u16x4* H4 = (u16x4*)H;

  size_t pidx = ((size_t)c * nbch + (size_t)bz * DIM_INNER) / 4 + ep;
  float4_t logh = ((const float4_t*)P)[pidx];
#pragma unroll 4
  for (int t = 0; t < CHUNK; t++) {
    uint4_t u = L4[base4 + (size_t)t * EQ];
    u16x4 hv;
#pragma unroll
    for (int k = 0; k < 4; k++) {
      float lc = bflo2f(u[k]), lv = bfhi2f(u[k]);
      logh[k] = logaddexp_f(lc + logh[k], lv);
      hv[k] = f2bf(__expf(logh[k]));
    }
    H4[base4 + (size_t)t * EQ] = hv;
  }
}

extern "C" void kernel_launch(void* const* d_in, const int* in_sizes, int n_in,
                              void* d_out, int out_size, void* d_ws, size_t ws_size,
                              hipStream_t stream) {
  const float* X = (const float*)d_in[0];     // [4,4096,1024]
  const float* Whg = (const float*)d_in[1];   // [1024,4096]
  const float* Wout = (const float*)d_in[2];  // [2048,1024]
  float* out = (float*)d_out;                 // [4,4096,1024] fp32

  ushort_t* Xbf = (ushort_t*)d_ws;
  ushort_t* Whg_t = Xbf + (size_t)MTOT * DIM;                   // [4096][1024]
  ushort_t* Wout_t = Whg_t + (size_t)(2 * DIM_INNER) * DIM;     // [1024][2048]
  char* pp = (char*)(Wout_t + (size_t)DIM * DIM_INNER);

  const size_t fixed_bytes = (size_t)MTOT * DIM * 2 +
                             (size_t)2 * DIM_INNER * DIM * 2 +
                             (size_t)DIM * DIM_INNER * 2;
  // per batch: LCLV 4B + H 2B per elem + 2 summaries
  const size_t per_batch = (size_t)SEQ * DIM_INNER * 4 +
                           (size_t)SEQ * DIM_INNER * 2 +
                           2 * (size_t)DIM_INNER * NCHUNK * 4;
  int nb = 4;
  while (nb > 1 && fixed_bytes + (size_t)nb * per_batch > ws_size) nb >>= 1;
  const int npass = BATCH / nb;

  convert_f32_bf16<<<(MTOT * DIM / 4) / 256, 256, 0, stream>>>(X, Xbf);
  transpose_f32_bf16<<<dim3(2 * DIM_INNER / 32, DIM / 32), 256, 0, stream>>>(
      Whg, Whg_t, DIM, 2 * DIM_INNER);
  transpose_f32_bf16<<<dim3(DIM / 32, DIM_INNER / 32), 256, 0, stream>>>(
      Wout, Wout_t, DIM_INNER, DIM);

  for (int pass = 0; pass < npass; pass++) {
    const int b0 = pass * nb;
    const int nrows = nb * SEQ;
    const int nbch = nb * DIM_INNER;

    unsigned int* LCLV = (unsigned int*)pp;
    ushort_t* Hbf = (ushort_t*)(LCLV + (size_t)nb * SEQ * DIM_INNER);
    float* Asum = (float*)(Hbf + (size_t)nb * SEQ * DIM_INNER);
    float* Lend = Asum + (size_t)nb * DIM_INNER * NCHUNK;

    gemm1_fused<<<dim3(DIM_INNER / 128, nrows / 256), 512, 0, stream>>>(
        Xbf + (size_t)b0 * SEQ * DIM, Whg_t, LCLV);
    scan_phase1<<<(nbch / 4 * NCHUNK) / 256, 256, 0, stream>>>(LCLV, Asum, Lend, nbch);
    scan_phase2<<<nbch / 256, 256, 0, stream>>>(Asum, Lend, nbch);
    scan_phase3<<<(nbch / 4 * NCHUNK) / 256, 256, 0, stream>>>(LCLV, Asum, Hbf, nbch);
    gemm2<<<dim3(DIM / 256, nrows / 256), 512, 0, stream>>>(
        Hbf, Wout_t, out + (size_t)b0 * SEQ * DIM);
  }
}